// Round 2
// baseline (302.849 us; speedup 1.0000x reference)
//
#include <hip/hip_runtime.h>

#define NCLS 18
#define TILE_ROWS 256
#define TILE_F2 (TILE_ROWS * NCLS / 2)   // 2304 float2 per array per tile

__global__ __launch_bounds__(256) void ce_soft_kernel(
    const float2* __restrict__ logits2,
    const float2* __restrict__ labels2,
    float* __restrict__ result,
    int B, float invB)
{
    // 36,864 B LDS -> 4 blocks/CU; tile-DMA of one block overlaps compute of others
    __shared__ float2 sX[TILE_F2];
    __shared__ float2 sL[TILE_F2];

    const int t = threadIdx.x;
    const int nTiles = (B + TILE_ROWS - 1) / TILE_ROWS;

    float acc = 0.0f;
    for (int tile = blockIdx.x; tile < nTiles; tile += gridDim.x) {
        const int rowBase = tile * TILE_ROWS;
        const int rows = min(TILE_ROWS, B - rowBase);
        const int n2 = rows * (NCLS / 2);              // float2 elems this tile
        const size_t g2 = (size_t)rowBase * (NCLS / 2);

        // coalesced staging: consecutive lanes -> consecutive float2 (512 B/wave-instr)
        for (int g = t; g < n2; g += 256) {
            sX[g] = logits2[g2 + g];
            sL[g] = labels2[g2 + g];
        }
        __syncthreads();

        if (t < rows) {
            const float2* xr = &sX[t * (NCLS / 2)];
            const float2* lr = &sL[t * (NCLS / 2)];
            float x[NCLS];
            #pragma unroll
            for (int j = 0; j < NCLS / 2; ++j) {
                float2 v = xr[j];
                x[2 * j] = v.x; x[2 * j + 1] = v.y;
            }
            float m = x[0];
            #pragma unroll
            for (int c = 1; c < NCLS; ++c) m = fmaxf(m, x[c]);

            float se = 0.0f, dot = 0.0f, sl = 0.0f;
            #pragma unroll
            for (int j = 0; j < NCLS / 2; ++j) {
                float2 w = lr[j];
                se += __expf(x[2 * j] - m) + __expf(x[2 * j + 1] - m);
                dot = fmaf(w.x, x[2 * j], dot);
                dot = fmaf(w.y, x[2 * j + 1], dot);
                sl += w.x + w.y;
            }
            float lse = m + __logf(se);
            // per_row = sl*lse - dot
            acc = fmaf(sl, lse, acc - dot);
        }
        __syncthreads();   // protect LDS before next tile's overwrite
    }

    // wave (64-lane) shuffle reduction
    #pragma unroll
    for (int off = 32; off > 0; off >>= 1)
        acc += __shfl_down(acc, off, 64);

    __shared__ float wave_sums[4];
    const int lane = t & 63;
    const int wid  = t >> 6;
    if (lane == 0) wave_sums[wid] = acc;
    __syncthreads();
    if (t == 0) {
        float s = wave_sums[0] + wave_sums[1] + wave_sums[2] + wave_sums[3];
        atomicAdd(result, s * invB);
    }
}

extern "C" void kernel_launch(void* const* d_in, const int* in_sizes, int n_in,
                              void* d_out, int out_size, void* d_ws, size_t ws_size,
                              hipStream_t stream) {
    const float2* logits2 = (const float2*)d_in[0];
    const float2* labels2 = (const float2*)d_in[1];
    float* result = (float*)d_out;

    int B = in_sizes[0] / NCLS;   // 2,000,000

    // d_out is poisoned with 0xAA before every launch; zero it for the atomic.
    hipMemsetAsync(d_out, 0, sizeof(float), stream);

    int block = 256;
    int grid  = 2048;             // grid-stride over 7813 tiles (~3.8 tiles/block)
    ce_soft_kernel<<<grid, block, 0, stream>>>(logits2, labels2, result, B, 1.0f / (float)B);
}

// Round 3
// 294.262 us; speedup vs baseline: 1.0292x; 1.0292x over previous
//
#include <hip/hip_runtime.h>

#define NCLS 18
#define TILE_ROWS 256
#define TILE_F2 (TILE_ROWS * NCLS / 2)   // 2304 float2 per array per tile
#define GRID_A 2048

__global__ __launch_bounds__(256) void ce_soft_kernel(
    const float2* __restrict__ logits2,
    const float2* __restrict__ labels2,
    float* __restrict__ partials,
    int B)
{
    __shared__ float2 sX[TILE_F2];
    __shared__ float2 sL[TILE_F2];

    const int t = threadIdx.x;
    const int nTiles = (B + TILE_ROWS - 1) / TILE_ROWS;

    float acc = 0.0f;
    for (int tile = blockIdx.x; tile < nTiles; tile += gridDim.x) {
        const int rowBase = tile * TILE_ROWS;
        const int rows = min(TILE_ROWS, B - rowBase);
        const int n2 = rows * (NCLS / 2);
        const size_t g2 = (size_t)rowBase * (NCLS / 2);

        for (int g = t; g < n2; g += 256) {
            sX[g] = logits2[g2 + g];
            sL[g] = labels2[g2 + g];
        }
        __syncthreads();

        if (t < rows) {
            const float2* xr = &sX[t * (NCLS / 2)];
            const float2* lr = &sL[t * (NCLS / 2)];
            float x[NCLS];
            #pragma unroll
            for (int j = 0; j < NCLS / 2; ++j) {
                float2 v = xr[j];
                x[2 * j] = v.x; x[2 * j + 1] = v.y;
            }
            float m = x[0];
            #pragma unroll
            for (int c = 1; c < NCLS; ++c) m = fmaxf(m, x[c]);

            float se = 0.0f, dot = 0.0f, sl = 0.0f;
            #pragma unroll
            for (int j = 0; j < NCLS / 2; ++j) {
                float2 w = lr[j];
                se += __expf(x[2 * j] - m) + __expf(x[2 * j + 1] - m);
                dot = fmaf(w.x, x[2 * j], dot);
                dot = fmaf(w.y, x[2 * j + 1], dot);
                sl += w.x + w.y;
            }
            float lse = m + __logf(se);
            acc = fmaf(sl, lse, acc - dot);    // per_row = sl*lse - dot
        }
        __syncthreads();
    }

    #pragma unroll
    for (int off = 32; off > 0; off >>= 1)
        acc += __shfl_down(acc, off, 64);

    __shared__ float wave_sums[4];
    const int lane = t & 63;
    const int wid  = t >> 6;
    if (lane == 0) wave_sums[wid] = acc;
    __syncthreads();
    if (t == 0)
        partials[blockIdx.x] = wave_sums[0] + wave_sums[1] + wave_sums[2] + wave_sums[3];
}

__global__ __launch_bounds__(256) void ce_reduce_kernel(
    const float* __restrict__ partials, float* __restrict__ out, int n, float invB)
{
    float acc = 0.0f;
    for (int i = threadIdx.x; i < n; i += 256) acc += partials[i];

    #pragma unroll
    for (int off = 32; off > 0; off >>= 1)
        acc += __shfl_down(acc, off, 64);

    __shared__ float wave_sums[4];
    const int lane = threadIdx.x & 63;
    const int wid  = threadIdx.x >> 6;
    if (lane == 0) wave_sums[wid] = acc;
    __syncthreads();
    if (threadIdx.x == 0)
        out[0] = (wave_sums[0] + wave_sums[1] + wave_sums[2] + wave_sums[3]) * invB;
}

extern "C" void kernel_launch(void* const* d_in, const int* in_sizes, int n_in,
                              void* d_out, int out_size, void* d_ws, size_t ws_size,
                              hipStream_t stream) {
    const float2* logits2 = (const float2*)d_in[0];
    const float2* labels2 = (const float2*)d_in[1];
    float* partials = (float*)d_ws;           // 2048 floats = 8 KB scratch
    float* result = (float*)d_out;

    int B = in_sizes[0] / NCLS;               // 2,000,000

    ce_soft_kernel<<<GRID_A, 256, 0, stream>>>(logits2, labels2, partials, B);
    ce_reduce_kernel<<<1, 256, 0, stream>>>(partials, result, GRID_A, 1.0f / (float)B);
}